// Round 4
// baseline (4482.684 us; speedup 1.0000x reference)
//
#include <hip/hip_runtime.h>
#include <math.h>

#define SENT 2.0f
#define NTOK 2048
#define EDIM 512
#define GJ   2048   // 4*HID
#define NW   32     // worker WGs (one XCD = 32 CUs)
#define HPW  16     // hidden units per worker WG
#define LOG2E 1.4426950408889634f

typedef float f32x4 __attribute__((ext_vector_type(4)));

__device__ __forceinline__ float sigm_f(float x) {
  return __builtin_amdgcn_rcpf(1.f + __builtin_amdgcn_exp2f(-LOG2E * x));
}
__device__ __forceinline__ float tanh_f(float x) {
  return 1.f - 2.f * __builtin_amdgcn_rcpf(1.f + __builtin_amdgcn_exp2f(2.f * LOG2E * x));
}

// ---------------- k_init: sentinel fill both H buffers + control init ----------------
__global__ __launch_bounds__(256) void k_init(float4* __restrict__ A4,
                                              float4* __restrict__ B4,
                                              int* __restrict__ ctl) {
  int i = blockIdx.x * blockDim.x + threadIdx.x;   // 262144 float4 = 2048*512 floats
  float4 s4 = make_float4(SENT, SENT, SENT, SENT);
  A4[i] = s4;
  B4[i] = s4;
  // ctl layout (ints): [0..7]=cnt  [8]=winner  [9]=okcnt  [10]=kill  [16..47]=probe
  if (blockIdx.x == 0 && threadIdx.x < 48) {
    int v = (threadIdx.x == 8) ? -1 : 0;
    ctl[threadIdx.x] = v;
  }
}

// ---------------- k_compact: stable compaction of selected tokens ----------------
__global__ __launch_bounds__(1024) void k_compact(const float* __restrict__ scores,
                                                  int* __restrict__ sel,
                                                  int* __restrict__ nselp) {
  __shared__ int cnt[1024];
  const int tid = threadIdx.x;
  const int i0 = tid * 2, i1 = tid * 2 + 1;
  const int m0 = (scores[i0] > 0.5f) ? 1 : 0;
  const int m1 = (scores[i1] > 0.5f) ? 1 : 0;
  cnt[tid] = m0 + m1;
  __syncthreads();
  for (int off = 1; off < 1024; off <<= 1) {
    int v = cnt[tid];
    int u = (tid >= off) ? cnt[tid - off] : 0;
    __syncthreads();
    cnt[tid] = v + u;
    __syncthreads();
  }
  int excl = (tid == 0) ? 0 : cnt[tid - 1];
  if (m0) sel[excl] = i0;
  if (m1) sel[excl + m0] = i1;
  if (tid == 1023) *nselp = cnt[1023];
}

// ---------------- k_gemm: C[t][j] = bias1[j](+bias2[j]) + sum_e Arow(t)[e]*B[j][e] ----------------
template<bool GATHER>
__global__ __launch_bounds__(256) void k_gemm(
    const float* __restrict__ A, const float* __restrict__ B,
    const float* __restrict__ bias1, const float* __restrict__ bias2,
    float* __restrict__ C, const int* __restrict__ sel,
    const int* __restrict__ nselp, int J)
{
  const int n_sel = *nselp;
  const int t0 = blockIdx.x * 32;
  if (t0 >= n_sel) return;
  const int j0 = blockIdx.y * 64;
  const int tid = threadIdx.x;
  __shared__ float As[32][36];
  __shared__ float Bst[32][68];
  __shared__ int rowsrc[32];
  if (tid < 32) {
    int t = t0 + tid;
    int r = -1;
    if (t < n_sel) r = GATHER ? sel[t] : t;
    rowsrc[tid] = r;
  }
  __syncthreads();
  const int tx = tid & 15;
  const int ty = tid >> 4;
  float4 acc0 = make_float4(0.f, 0.f, 0.f, 0.f);
  float4 acc1 = make_float4(0.f, 0.f, 0.f, 0.f);
  for (int e0 = 0; e0 < EDIM; e0 += 32) {
    {
      int t = tid >> 3, e4 = tid & 7;
      int r = rowsrc[t];
      float4 v = make_float4(0.f, 0.f, 0.f, 0.f);
      if (r >= 0) v = ((const float4*)(A + (size_t)r * EDIM + e0))[e4];
      *(float4*)&As[t][e4 * 4] = v;
    }
    #pragma unroll
    for (int l = 0; l < 2; ++l) {
      int idx = tid + l * 256;
      int j = idx >> 3, e4 = idx & 7;
      float4 v = ((const float4*)(B + (size_t)(j0 + j) * EDIM + e0))[e4];
      Bst[e4 * 4 + 0][j] = v.x; Bst[e4 * 4 + 1][j] = v.y;
      Bst[e4 * 4 + 2][j] = v.z; Bst[e4 * 4 + 3][j] = v.w;
    }
    __syncthreads();
    #pragma unroll
    for (int e = 0; e < 32; ++e) {
      float a0 = As[ty * 2 + 0][e];
      float a1 = As[ty * 2 + 1][e];
      float4 b = *(const float4*)&Bst[e][tx * 4];
      acc0.x += a0 * b.x; acc0.y += a0 * b.y; acc0.z += a0 * b.z; acc0.w += a0 * b.w;
      acc1.x += a1 * b.x; acc1.y += a1 * b.y; acc1.z += a1 * b.z; acc1.w += a1 * b.w;
    }
    __syncthreads();
  }
  float4 bv = ((const float4*)bias1)[(j0 >> 2) + tx];
  if (bias2) {
    float4 b2 = ((const float4*)bias2)[(j0 >> 2) + tx];
    bv.x += b2.x; bv.y += b2.y; bv.z += b2.z; bv.w += b2.w;
  }
  #pragma unroll
  for (int i = 0; i < 2; ++i) {
    int t = t0 + ty * 2 + i;
    if (t < n_sel) {
      float4 a = (i == 0) ? acc0 : acc1;
      float4 r = make_float4(a.x + bv.x, a.y + bv.y, a.z + bv.z, a.w + bv.w);
      *(float4*)(C + (size_t)t * J + j0 + tx * 4) = r;
    }
  }
}

// ---------------- k_lstm: persistent recurrence, verified XCD-local fast path ----------------
// 256 WGs launched; 32 self-select (XCC_ID rank + winner CAS, bounded, -2 fallback).
// VERIFICATION: each worker plain-stores probe[rank]; all sc0-poll all 32 (bounded);
// consensus okcnt/kill at agent scope -> fast mode only if plain-store->sc0-load is
// proven live for these 32 WGs. Producers ALWAYS dual-store (A plain, B agent) so the
// proven agent-scope B-poll fallback always terminates. All other loops bounded.
// Role split: waves 0,2 poll/stage (never store -> clean vmcnt); wave 1 lanes 0..15
// do Gin prefetch + gates + h stores (never polls -> store-acks off critical path).
__global__ __launch_bounds__(512, 1) void k_lstm(
    const float* __restrict__ Gin, float* __restrict__ HoutA,
    float* __restrict__ HoutB, const float* __restrict__ Whh,
    const int* __restrict__ nselp, int* __restrict__ ctl)
{
  const int tid = threadIdx.x;
  const int n_sel = *nselp;
  if (n_sel <= 0) return;

  int* cnt    = ctl;        // [0..7]
  int* winner = ctl + 8;
  int* okcnt  = ctl + 9;
  int* kill   = ctl + 10;
  int* probe  = ctl + 16;   // [16..47]

  __shared__ int s_slice, s_mode;
  if (tid == 0) {
    int xcd;
    asm("s_getreg_b32 %0, hwreg(HW_REG_XCC_ID)" : "=s"(xcd));
    xcd &= 7;
    int rank = atomicAdd(&cnt[xcd], 1);
    if (rank == NW - 1) atomicCAS(winner, -1, xcd);
    int w = __hip_atomic_load(winner, __ATOMIC_RELAXED, __HIP_MEMORY_SCOPE_AGENT);
    for (int i = 0; i < 8000 && w == -1; ++i)
      w = __hip_atomic_load(winner, __ATOMIC_RELAXED, __HIP_MEMORY_SCOPE_AGENT);
    if (w == -1) {
      int old = atomicCAS(winner, -1, -2);
      w = (old == -1) ? -2 : old;
    }
    if (w == -2) { s_mode = 1; s_slice = (blockIdx.x < NW) ? (int)blockIdx.x : -1; }
    else         { s_mode = 0; s_slice = (w == xcd && rank < NW) ? rank : -1; }
  }
  __syncthreads();
  const int r = s_slice;
  if (r < 0) return;

  // ---- verification handshake (LOCAL mode only) ----
  __shared__ int s_fast;
  if (s_mode == 0) {
    if (tid == 0) {
      int one = 1;
      asm volatile("global_store_dword %0, %1, off" :: "v"(probe + r), "v"(one) : "memory");
    }
    if (tid < 64) {
      int seen = 1;
      if (tid < NW) {
        seen = 0;
        for (int i = 0; i < 4000 && !seen; ++i) {
          int x;
          asm volatile("global_load_dword %0, %1, off sc0\n\t"
                       "s_waitcnt vmcnt(0)"
                       : "=v"(x) : "v"(probe + tid) : "memory");
          seen = (x == 1);
        }
      }
      unsigned long long m = __ballot(seen);
      if (tid == 0) {
        if (m == ~0ull) atomicAdd(okcnt, 1);
        else atomicExch(kill, 1);
        int f = -1;
        for (int i = 0; i < 30000 && f < 0; ++i) {
          if (__hip_atomic_load(kill, __ATOMIC_RELAXED, __HIP_MEMORY_SCOPE_AGENT)) f = 0;
          else if (__hip_atomic_load(okcnt, __ATOMIC_RELAXED, __HIP_MEMORY_SCOPE_AGENT) == NW) f = 1;
        }
        if (f < 0) { atomicExch(kill, 1); f = 0; }
        s_fast = f;
      }
    }
  } else if (tid == 0) {
    s_fast = 0;
  }
  __syncthreads();

  // ---- roles ----
  const int q = (tid < 64) ? tid : ((tid >= 128 && tid < 192) ? tid - 64 : -1);  // poll quad
  const bool gatel = (tid >= 64 && tid < 80);                                    // gate lane
  const int u = tid & 15;                                                        // unit in slice

  const int row_local = tid >> 3;        // 0..63
  const int sub = tid & 7;
  const int g = row_local >> 4;          // gate 0..3 (i,f,g,o)
  const int jl = row_local & 15;
  const int grow = g * 512 + r * HPW + jl;
  const int c0 = sub * 64;
  float4 wv[16];
  {
    const float4* wp = (const float4*)(Whh + (size_t)grow * 512 + c0);
    #pragma unroll
    for (int k = 0; k < 16; ++k) wv[k] = wp[(k + sub) & 15];
  }
  __shared__ float hl[512];
  __shared__ float gsum[64];
  float cst = 0.f;
  int fastb = s_fast;
  int miss = 0;
  float gx0 = 0.f, gx1 = 0.f, gx2 = 0.f, gx3 = 0.f;
  if (gatel) {
    const float* gr = Gin + r * HPW + u;
    gx0 = gr[0]; gx1 = gr[512]; gx2 = gr[1024]; gx3 = gr[1536];
  }
  for (int t = 0; t < n_sel; ++t) {
    float nx0 = 0.f, nx1 = 0.f, nx2 = 0.f, nx3 = 0.f;
    if (gatel && t + 1 < n_sel) {
      const float* gr = Gin + (size_t)(t + 1) * GJ + r * HPW + u;
      nx0 = gr[0]; nx1 = gr[512]; nx2 = gr[1024]; nx3 = gr[1536];
    }
    if (q >= 0) {
      if (t == 0) {
        *(float4*)&hl[q * 4] = make_float4(0.f, 0.f, 0.f, 0.f);
        if (fastb) {   // warm line 0 in local L2 (one-time)
          float junk;
          asm volatile("global_load_dword %0, %1, off sc0\n\t"
                       "s_waitcnt vmcnt(0)"
                       : "=v"(junk) : "v"(HoutA + q * 4) : "memory");
        }
      } else {
        const float* srcA = HoutA + (size_t)(t - 1) * 512 + q * 4;
        const float* srcB = HoutB + (size_t)(t - 1) * 512 + q * 4;
        f32x4 v;
        bool got = false;
        if (fastb) {
          float junk;
          // iteration 0: poll quad + touch next step's line in one round trip
          asm volatile("global_load_dwordx4 %0, %2, off sc0\n\t"
                       "global_load_dword %1, %3, off sc0\n\t"
                       "s_waitcnt vmcnt(0)"
                       : "=v"(v), "=v"(junk)
                       : "v"(srcA), "v"(srcA + 512) : "memory");
          got = (v[0] != SENT && v[1] != SENT && v[2] != SENT && v[3] != SENT);
          for (int i = 0; i < 384 && !got; ++i) {
            asm volatile("global_load_dwordx4 %0, %1, off sc0\n\t"
                         "s_waitcnt vmcnt(0)"
                         : "=v"(v) : "v"(srcA) : "memory");
            got = (v[0] != SENT && v[1] != SENT && v[2] != SENT && v[3] != SENT);
          }
          if (!got && ++miss >= 8) fastb = 0;   // fast path systematically sad -> kill
        }
        if (!got) {
          float a, b, c2, d;
          do {   // proven agent-scope path; producers dual-store in all modes
            a  = __hip_atomic_load(srcB + 0, __ATOMIC_RELAXED, __HIP_MEMORY_SCOPE_AGENT);
            b  = __hip_atomic_load(srcB + 1, __ATOMIC_RELAXED, __HIP_MEMORY_SCOPE_AGENT);
            c2 = __hip_atomic_load(srcB + 2, __ATOMIC_RELAXED, __HIP_MEMORY_SCOPE_AGENT);
            d  = __hip_atomic_load(srcB + 3, __ATOMIC_RELAXED, __HIP_MEMORY_SCOPE_AGENT);
          } while (a == SENT || b == SENT || c2 == SENT || d == SENT);
          v[0] = a; v[1] = b; v[2] = c2; v[3] = d;
        }
        *(f32x4*)&hl[q * 4] = v;
      }
    }
    __syncthreads();
    // partial dot over 64 cols, sub-rotated, 4 accumulators
    const float4* hv = (const float4*)&hl[c0];
    float s0 = 0.f, s1 = 0.f, s2 = 0.f, s3 = 0.f;
    #pragma unroll
    for (int k = 0; k < 4; ++k) {
      float4 w4, h4;
      w4 = wv[4*k+0]; h4 = hv[(4*k+0+sub)&15]; s0 += w4.x*h4.x + w4.y*h4.y + w4.z*h4.z + w4.w*h4.w;
      w4 = wv[4*k+1]; h4 = hv[(4*k+1+sub)&15]; s1 += w4.x*h4.x + w4.y*h4.y + w4.z*h4.z + w4.w*h4.w;
      w4 = wv[4*k+2]; h4 = hv[(4*k+2+sub)&15]; s2 += w4.x*h4.x + w4.y*h4.y + w4.z*h4.z + w4.w*h4.w;
      w4 = wv[4*k+3]; h4 = hv[(4*k+3+sub)&15]; s3 += w4.x*h4.x + w4.y*h4.y + w4.z*h4.z + w4.w*h4.w;
    }
    float s = (s0 + s1) + (s2 + s3);
    s += __shfl_xor(s, 1); s += __shfl_xor(s, 2); s += __shfl_xor(s, 4);
    if (sub == 0) gsum[row_local] = s;
    __syncthreads();
    if (gatel) {
      float gi = gx0 + gsum[u];
      float gf = gx1 + gsum[16 + u];
      float gg = gx2 + gsum[32 + u];
      float go = gx3 + gsum[48 + u];
      float ig = sigm_f(gi);
      float fg = sigm_f(gf);
      float og = sigm_f(go);
      cst = fg * cst + ig * tanh_f(gg);
      float h = og * tanh_f(cst);   // in (-1,1): sentinel 2.0f unreachable
      float* dA = HoutA + (size_t)t * 512 + r * HPW + u;
      float* dB = HoutB + (size_t)t * 512 + r * HPW + u;
      asm volatile("global_store_dword %0, %1, off" :: "v"(dA), "v"(h) : "memory");
      __hip_atomic_store(dB, h, __ATOMIC_RELAXED, __HIP_MEMORY_SCOPE_AGENT);
      gx0 = nx0; gx1 = nx1; gx2 = nx2; gx3 = nx3;
    }
  }
}

// ---------------- k_norms: row L2 norms (memory keys + queries) ----------------
__global__ __launch_bounds__(256) void k_norms(
    const float* __restrict__ memo, const float* __restrict__ qe,
    float* __restrict__ dens, const int* __restrict__ nselp)
{
  const int n_sel = *nselp;
  const int row = blockIdx.x * 4 + (threadIdx.x >> 6);
  const int lane = threadIdx.x & 63;
  const float* src;
  if (row < NTOK) {
    if (row >= n_sel) return;
    src = memo + (size_t)row * EDIM;
  } else {
    if (row >= NTOK + 256) return;
    src = qe + (size_t)(row - NTOK) * EDIM;
  }
  const float4* s4 = (const float4*)src;
  float4 a = s4[lane], b = s4[lane + 64];
  float s = a.x*a.x + a.y*a.y + a.z*a.z + a.w*a.w
          + b.x*b.x + b.y*b.y + b.z*b.z + b.w*b.w;
  #pragma unroll
  for (int off = 32; off; off >>= 1) s += __shfl_xor(s, off);
  if (lane == 0) dens[row] = fmaxf(sqrtf(s), 1e-12f);
}

// ---------------- k_retrieve: sims + top-k + gather (4 queries per block) ----------------
__global__ __launch_bounds__(256) void k_retrieve(
    const float* __restrict__ memo, const float* __restrict__ qe,
    const float* __restrict__ dens, const float* __restrict__ values,
    const int* __restrict__ sel, const int* __restrict__ nselp,
    float* __restrict__ out, int top_k)
{
  const int n_sel = *nselp;
  const int qb = blockIdx.x * 4;
  const int tid = threadIdx.x;
  __shared__ float qs[4][EDIM];
  __shared__ float sims[4][NTOK];
  __shared__ int tix[4][8];
  for (int l = tid; l < 512; l += 256) {
    int q = l >> 7, e4 = l & 127;
    float4 v = ((const float4*)(qe + (size_t)(qb + q) * EDIM))[e4];
    float inv = 1.f / dens[NTOK + qb + q];
    v.x *= inv; v.y *= inv; v.z *= inv; v.w *= inv;
    *(float4*)&qs[q][e4 * 4] = v;
  }
  __syncthreads();
  for (int t = tid; t < n_sel; t += 256) {
    const float4* m4 = (const float4*)(memo + (size_t)t * EDIM);
    float a0 = 0.f, a1 = 0.f, a2 = 0.f, a3 = 0.f;
    for (int e4 = 0; e4 < 128; ++e4) {
      float4 m = m4[e4];
      float4 q0 = *(const float4*)&qs[0][e4 * 4];
      float4 q1 = *(const float4*)&qs[1][e4 * 4];
      float4 q2 = *(const float4*)&qs[2][e4 * 4];
      float4 q3 = *(const float4*)&qs[3][e4 * 4];
      a0 += m.x*q0.x + m.y*q0.y + m.z*q0.z + m.w*q0.w;
      a1 += m.x*q1.x + m.y*q1.y + m.z*q1.z + m.w*q1.w;
      a2 += m.x*q2.x + m.y*q2.y + m.z*q2.z + m.w*q2.w;
      a3 += m.x*q3.x + m.y*q3.y + m.z*q3.z + m.w*q3.w;
    }
    float inv = 1.f / dens[t];
    sims[0][t] = a0 * inv; sims[1][t] = a1 * inv;
    sims[2][t] = a2 * inv; sims[3][t] = a3 * inv;
  }
  __syncthreads();
  const int wq = tid >> 6, lane = tid & 63;
  for (int r = 0; r < top_k; ++r) {
    if (r < n_sel) {
      float bv = -INFINITY; int bi = 0x7fffffff;
      for (int t = lane; t < n_sel; t += 64) {
        float v = sims[wq][t];
        if (v > bv || (v == bv && t < bi)) { bv = v; bi = t; }
      }
      #pragma unroll
      for (int off = 32; off; off >>= 1) {
        float ov = __shfl_xor(bv, off);
        int   oi = __shfl_xor(bi, off);
        if (ov > bv || (ov == bv && oi < bi)) { bv = ov; bi = oi; }
      }
      if (lane == 0) { tix[wq][r] = bi; sims[wq][bi] = -INFINITY; }
    } else if (lane == 0) {
      tix[wq][r] = -1;
    }
    __syncthreads();
  }
  const int tot = 4 * top_k * 128;
  for (int l = tid; l < tot; l += 256) {
    int q = l / (top_k * 128);
    int rem = l - q * top_k * 128;
    int r = rem >> 7;
    int e4 = rem & 127;
    int t = tix[q][r];
    float4 v = make_float4(0.f, 0.f, 0.f, 0.f);
    if (t >= 0) v = ((const float4*)(values + (size_t)sel[t] * EDIM))[e4];
    ((float4*)out)[(((size_t)(qb + q) * top_k) + r) * 128 + e4] = v;
  }
}

extern "C" void kernel_launch(void* const* d_in, const int* in_sizes, int n_in,
                              void* d_out, int out_size, void* d_ws, size_t ws_size,
                              hipStream_t stream) {
  const float* keys   = (const float*)d_in[0];
  const float* values = (const float*)d_in[1];
  const float* scores = (const float*)d_in[2];
  const float* qe     = (const float*)d_in[3];
  const float* W_ih   = (const float*)d_in[6];
  const float* W_hh   = (const float*)d_in[7];
  const float* b_ih   = (const float*)d_in[8];
  const float* b_hh   = (const float*)d_in[9];
  const float* W_out  = (const float*)d_in[10];
  const float* b_out  = (const float*)d_in[11];
  float* out = (float*)d_out;
  const int top_k = out_size / (256 * 512);   // = 8

  char* ws = (char*)d_ws;
  int*   nsel   = (int*)ws;                             // 4 B
  int*   ctl    = (int*)(ws + 128);                     // 48 ints: cnt/winner/okcnt/kill/probe
  int*   sel    = (int*)(ws + 4096);                    // 8 KB
  float* dens   = (float*)(ws + 16384);                 // 9 KB
  float* HoutA  = (float*)(ws + (size_t)(1u << 20));    // 4 MB  [1M,5M)
  float* HoutB  = (float*)(ws + (size_t)(5u << 20));    // 4 MB  [5M,9M)
  float* Gin    = (float*)(ws + (size_t)(9u << 20));    // 16 MB [9M,25M)
  float* memo   = (float*)(ws + (size_t)(9u << 20));    // 4 MB, aliases Gin (dead by then)
  (void)in_sizes; (void)n_in; (void)ws_size;

  k_init<<<1024, 256, 0, stream>>>((float4*)HoutA, (float4*)HoutB, ctl);
  k_compact<<<1, 1024, 0, stream>>>(scores, sel, nsel);
  k_gemm<true ><<<dim3(64, 32), 256, 0, stream>>>(keys, W_ih, b_ih, b_hh, Gin, sel, nsel, GJ);
  k_lstm<<<256, 512, 0, stream>>>(Gin, HoutA, HoutB, W_hh, nsel, ctl);
  k_gemm<false><<<dim3(64, 8), 256, 0, stream>>>(HoutB, W_out, b_out, nullptr, memo, nullptr, nsel, EDIM);
  k_norms<<<576, 256, 0, stream>>>(memo, qe, dens, nsel);
  k_retrieve<<<64, 256, 0, stream>>>(memo, qe, dens, values, sel, nsel, out, top_k);
}

// Round 5
// 1913.998 us; speedup vs baseline: 2.3421x; 2.3421x over previous
//
#include <hip/hip_runtime.h>
#include <math.h>

#define SENT 2.0f
#define NTOK 2048
#define EDIM 512
#define GJ   2048   // 4*HID
#define NW   32     // worker WGs
#define HPW  16     // hidden units per WG
#define LOG2E 1.4426950408889634f

typedef float f32x4 __attribute__((ext_vector_type(4)));

__device__ __forceinline__ float sigm_f(float x) {
  return __builtin_amdgcn_rcpf(1.f + __builtin_amdgcn_exp2f(-LOG2E * x));
}
__device__ __forceinline__ float tanh_f(float x) {
  return 1.f - 2.f * __builtin_amdgcn_rcpf(1.f + __builtin_amdgcn_exp2f(2.f * LOG2E * x));
}

// ---------------- k_init: sentinel fill ----------------
__global__ __launch_bounds__(256) void k_init(float4* __restrict__ H4) {
  int i = blockIdx.x * blockDim.x + threadIdx.x;   // 262144 float4 = 2048*512 floats
  H4[i] = make_float4(SENT, SENT, SENT, SENT);
}

// ---------------- k_compact: stable compaction of selected tokens ----------------
__global__ __launch_bounds__(1024) void k_compact(const float* __restrict__ scores,
                                                  int* __restrict__ sel,
                                                  int* __restrict__ nselp) {
  __shared__ int cnt[1024];
  const int tid = threadIdx.x;
  const int i0 = tid * 2, i1 = tid * 2 + 1;
  const int m0 = (scores[i0] > 0.5f) ? 1 : 0;
  const int m1 = (scores[i1] > 0.5f) ? 1 : 0;
  cnt[tid] = m0 + m1;
  __syncthreads();
  for (int off = 1; off < 1024; off <<= 1) {
    int v = cnt[tid];
    int u = (tid >= off) ? cnt[tid - off] : 0;
    __syncthreads();
    cnt[tid] = v + u;
    __syncthreads();
  }
  int excl = (tid == 0) ? 0 : cnt[tid - 1];
  if (m0) sel[excl] = i0;
  if (m1) sel[excl + m0] = i1;
  if (tid == 1023) *nselp = cnt[1023];
}

// ---------------- k_gemm: C[t][j] = bias1[j](+bias2[j]) + sum_e Arow(t)[e]*B[j][e] ----------------
template<bool GATHER>
__global__ __launch_bounds__(256) void k_gemm(
    const float* __restrict__ A, const float* __restrict__ B,
    const float* __restrict__ bias1, const float* __restrict__ bias2,
    float* __restrict__ C, const int* __restrict__ sel,
    const int* __restrict__ nselp, int J)
{
  const int n_sel = *nselp;
  const int t0 = blockIdx.x * 32;
  if (t0 >= n_sel) return;
  const int j0 = blockIdx.y * 64;
  const int tid = threadIdx.x;
  __shared__ float As[32][36];
  __shared__ float Bst[32][68];
  __shared__ int rowsrc[32];
  if (tid < 32) {
    int t = t0 + tid;
    int r = -1;
    if (t < n_sel) r = GATHER ? sel[t] : t;
    rowsrc[tid] = r;
  }
  __syncthreads();
  const int tx = tid & 15;
  const int ty = tid >> 4;
  float4 acc0 = make_float4(0.f, 0.f, 0.f, 0.f);
  float4 acc1 = make_float4(0.f, 0.f, 0.f, 0.f);
  for (int e0 = 0; e0 < EDIM; e0 += 32) {
    {
      int t = tid >> 3, e4 = tid & 7;
      int r = rowsrc[t];
      float4 v = make_float4(0.f, 0.f, 0.f, 0.f);
      if (r >= 0) v = ((const float4*)(A + (size_t)r * EDIM + e0))[e4];
      *(float4*)&As[t][e4 * 4] = v;
    }
    #pragma unroll
    for (int l = 0; l < 2; ++l) {
      int idx = tid + l * 256;
      int j = idx >> 3, e4 = idx & 7;
      float4 v = ((const float4*)(B + (size_t)(j0 + j) * EDIM + e0))[e4];
      Bst[e4 * 4 + 0][j] = v.x; Bst[e4 * 4 + 1][j] = v.y;
      Bst[e4 * 4 + 2][j] = v.z; Bst[e4 * 4 + 3][j] = v.w;
    }
    __syncthreads();
    #pragma unroll
    for (int e = 0; e < 32; ++e) {
      float a0 = As[ty * 2 + 0][e];
      float a1 = As[ty * 2 + 1][e];
      float4 b = *(const float4*)&Bst[e][tx * 4];
      acc0.x += a0 * b.x; acc0.y += a0 * b.y; acc0.z += a0 * b.z; acc0.w += a0 * b.w;
      acc1.x += a1 * b.x; acc1.y += a1 * b.y; acc1.z += a1 * b.z; acc1.w += a1 * b.w;
    }
    __syncthreads();
  }
  float4 bv = ((const float4*)bias1)[(j0 >> 2) + tx];
  if (bias2) {
    float4 b2 = ((const float4*)bias2)[(j0 >> 2) + tx];
    bv.x += b2.x; bv.y += b2.y; bv.z += b2.z; bv.w += b2.w;
  }
  #pragma unroll
  for (int i = 0; i < 2; ++i) {
    int t = t0 + ty * 2 + i;
    if (t < n_sel) {
      float4 a = (i == 0) ? acc0 : acc1;
      float4 r = make_float4(a.x + bv.x, a.y + bv.y, a.z + bv.z, a.w + bv.w);
      *(float4*)(C + (size_t)t * J + j0 + tx * 4) = r;
    }
  }
}

// ---------------- k_lstm: persistent recurrence, agent-scope dataflow (r3-proven) ----------------
// 32 WGs x 512 threads, 1/CU (co-resident). WG w owns units [w*16, w*16+16).
// Role split: tid<128 = pollers (one quad each; NEVER store -> poll vmcnt never
// drains store-acks); tid 128..143 = gate lanes (Gin prefetch + gates + h store;
// NEVER poll -> store-acks drain during next dot). All 512 threads do the dot.
// h handoff: agent-scope store -> L3; agent-scope sentinel poll (r1/r3-proven).
__global__ __launch_bounds__(512, 1) void k_lstm(
    const float* __restrict__ Gin, float* __restrict__ Hout,
    const float* __restrict__ Whh, const int* __restrict__ nselp)
{
  const int tid = threadIdx.x;
  const int n_sel = *nselp;
  if (n_sel <= 0) return;
  const int w = blockIdx.x;

  const int row_local = tid >> 3;        // 0..63
  const int sub = tid & 7;
  const int g = row_local >> 4;          // gate 0..3 (i,f,g,o)
  const int jl = row_local & 15;         // unit within slice
  const int grow = g * 512 + w * HPW + jl;
  const int c0 = sub * 64;
  float4 wv[16];
  {
    const float4* wp = (const float4*)(Whh + (size_t)grow * 512 + c0);
    #pragma unroll
    for (int k = 0; k < 16; ++k) wv[k] = wp[(k + sub) & 15];
  }

  // roles
  const int q = (tid < 128) ? tid : -1;                 // poller quad index
  const bool ownq = (q >= w * 4 && q < w * 4 + 4);      // own slice: filled via LDS by gates
  const bool gatel = (tid >= 128 && tid < 128 + HPW);   // gate lane (wave 2)
  const int u = tid - 128;                              // unit for gate lane

  __shared__ float hl[512];
  __shared__ float gsum[64];
  float cst = 0.f;
  float gx0 = 0.f, gx1 = 0.f, gx2 = 0.f, gx3 = 0.f;
  if (gatel) {
    const float* gr = Gin + w * HPW + u;
    gx0 = gr[0]; gx1 = gr[512]; gx2 = gr[1024]; gx3 = gr[1536];
    hl[w * HPW + u] = 0.f;   // own slice, step 0 (pre-sync#1: same window as pollers)
  }
  for (int t = 0; t < n_sel; ++t) {
    float nx0 = 0.f, nx1 = 0.f, nx2 = 0.f, nx3 = 0.f;
    if (gatel && t + 1 < n_sel) {
      const float* gr = Gin + (size_t)(t + 1) * GJ + w * HPW + u;
      nx0 = gr[0]; nx1 = gr[512]; nx2 = gr[1024]; nx3 = gr[1536];
    }
    if (q >= 0 && !ownq) {   // stage h_{t-1} from other WGs (agent-scope poll)
      if (t == 0) {
        *(float4*)&hl[q * 4] = make_float4(0.f, 0.f, 0.f, 0.f);
      } else {
        const float* src = Hout + (size_t)(t - 1) * 512 + q * 4;
        float a, b, c2, d;
        do {   // producers co-resident by construction -> terminates
          a  = __hip_atomic_load(src + 0, __ATOMIC_RELAXED, __HIP_MEMORY_SCOPE_AGENT);
          b  = __hip_atomic_load(src + 1, __ATOMIC_RELAXED, __HIP_MEMORY_SCOPE_AGENT);
          c2 = __hip_atomic_load(src + 2, __ATOMIC_RELAXED, __HIP_MEMORY_SCOPE_AGENT);
          d  = __hip_atomic_load(src + 3, __ATOMIC_RELAXED, __HIP_MEMORY_SCOPE_AGENT);
        } while (a == SENT || b == SENT || c2 == SENT || d == SENT);
        hl[q * 4 + 0] = a; hl[q * 4 + 1] = b;
        hl[q * 4 + 2] = c2; hl[q * 4 + 3] = d;
      }
    }
    __syncthreads();
    // partial dot over 64 cols, sub-rotated, 4 accumulators
    const float4* hv = (const float4*)&hl[c0];
    float s0 = 0.f, s1 = 0.f, s2 = 0.f, s3 = 0.f;
    #pragma unroll
    for (int k = 0; k < 4; ++k) {
      float4 w4, h4;
      w4 = wv[4*k+0]; h4 = hv[(4*k+0+sub)&15]; s0 += w4.x*h4.x + w4.y*h4.y + w4.z*h4.z + w4.w*h4.w;
      w4 = wv[4*k+1]; h4 = hv[(4*k+1+sub)&15]; s1 += w4.x*h4.x + w4.y*h4.y + w4.z*h4.z + w4.w*h4.w;
      w4 = wv[4*k+2]; h4 = hv[(4*k+2+sub)&15]; s2 += w4.x*h4.x + w4.y*h4.y + w4.z*h4.z + w4.w*h4.w;
      w4 = wv[4*k+3]; h4 = hv[(4*k+3+sub)&15]; s3 += w4.x*h4.x + w4.y*h4.y + w4.z*h4.z + w4.w*h4.w;
    }
    float s = (s0 + s1) + (s2 + s3);
    s += __shfl_xor(s, 1); s += __shfl_xor(s, 2); s += __shfl_xor(s, 4);
    if (sub == 0) gsum[row_local] = s;
    __syncthreads();
    if (gatel) {
      float gi = gx0 + gsum[u];
      float gf = gx1 + gsum[16 + u];
      float gg = gx2 + gsum[32 + u];
      float go = gx3 + gsum[48 + u];
      float ig = sigm_f(gi);
      float fg = sigm_f(gf);
      float og = sigm_f(go);
      cst = fg * cst + ig * tanh_f(gg);
      float h = og * tanh_f(cst);   // in (-1,1): sentinel 2.0f unreachable
      __hip_atomic_store(Hout + (size_t)t * 512 + w * HPW + u, h,
                         __ATOMIC_RELAXED, __HIP_MEMORY_SCOPE_AGENT);
      hl[w * HPW + u] = h;          // own slice bypasses L3 (post-sync#2 window, safe)
      gx0 = nx0; gx1 = nx1; gx2 = nx2; gx3 = nx3;
    }
  }
}

// ---------------- k_norms: row L2 norms (memory keys + queries) ----------------
__global__ __launch_bounds__(256) void k_norms(
    const float* __restrict__ memo, const float* __restrict__ qe,
    float* __restrict__ dens, const int* __restrict__ nselp)
{
  const int n_sel = *nselp;
  const int row = blockIdx.x * 4 + (threadIdx.x >> 6);
  const int lane = threadIdx.x & 63;
  const float* src;
  if (row < NTOK) {
    if (row >= n_sel) return;
    src = memo + (size_t)row * EDIM;
  } else {
    if (row >= NTOK + 256) return;
    src = qe + (size_t)(row - NTOK) * EDIM;
  }
  const float4* s4 = (const float4*)src;
  float4 a = s4[lane], b = s4[lane + 64];
  float s = a.x*a.x + a.y*a.y + a.z*a.z + a.w*a.w
          + b.x*b.x + b.y*b.y + b.z*b.z + b.w*b.w;
  #pragma unroll
  for (int off = 32; off; off >>= 1) s += __shfl_xor(s, off);
  if (lane == 0) dens[row] = fmaxf(sqrtf(s), 1e-12f);
}

// ---------------- k_retrieve: sims + top-k + gather (4 queries per block) ----------------
__global__ __launch_bounds__(256) void k_retrieve(
    const float* __restrict__ memo, const float* __restrict__ qe,
    const float* __restrict__ dens, const float* __restrict__ values,
    const int* __restrict__ sel, const int* __restrict__ nselp,
    float* __restrict__ out, int top_k)
{
  const int n_sel = *nselp;
  const int qb = blockIdx.x * 4;
  const int tid = threadIdx.x;
  __shared__ float qs[4][EDIM];
  __shared__ float sims[4][NTOK];
  __shared__ int tix[4][8];
  for (int l = tid; l < 512; l += 256) {
    int q = l >> 7, e4 = l & 127;
    float4 v = ((const float4*)(qe + (size_t)(qb + q) * EDIM))[e4];
    float inv = 1.f / dens[NTOK + qb + q];
    v.x *= inv; v.y *= inv; v.z *= inv; v.w *= inv;
    *(float4*)&qs[q][e4 * 4] = v;
  }
  __syncthreads();
  for (int t = tid; t < n_sel; t += 256) {
    const float4* m4 = (const float4*)(memo + (size_t)t * EDIM);
    float a0 = 0.f, a1 = 0.f, a2 = 0.f, a3 = 0.f;
    for (int e4 = 0; e4 < 128; ++e4) {
      float4 m = m4[e4];
      float4 q0 = *(const float4*)&qs[0][e4 * 4];
      float4 q1 = *(const float4*)&qs[1][e4 * 4];
      float4 q2 = *(const float4*)&qs[2][e4 * 4];
      float4 q3 = *(const float4*)&qs[3][e4 * 4];
      a0 += m.x*q0.x + m.y*q0.y + m.z*q0.z + m.w*q0.w;
      a1 += m.x*q1.x + m.y*q1.y + m.z*q1.z + m.w*q1.w;
      a2 += m.x*q2.x + m.y*q2.y + m.z*q2.z + m.w*q2.w;
      a3 += m.x*q3.x + m.y*q3.y + m.z*q3.z + m.w*q3.w;
    }
    float inv = 1.f / dens[t];
    sims[0][t] = a0 * inv; sims[1][t] = a1 * inv;
    sims[2][t] = a2 * inv; sims[3][t] = a3 * inv;
  }
  __syncthreads();
  const int wq = tid >> 6, lane = tid & 63;
  for (int r = 0; r < top_k; ++r) {
    if (r < n_sel) {
      float bv = -INFINITY; int bi = 0x7fffffff;
      for (int t = lane; t < n_sel; t += 64) {
        float v = sims[wq][t];
        if (v > bv || (v == bv && t < bi)) { bv = v; bi = t; }
      }
      #pragma unroll
      for (int off = 32; off; off >>= 1) {
        float ov = __shfl_xor(bv, off);
        int   oi = __shfl_xor(bi, off);
        if (ov > bv || (ov == bv && oi < bi)) { bv = ov; bi = oi; }
      }
      if (lane == 0) { tix[wq][r] = bi; sims[wq][bi] = -INFINITY; }
    } else if (lane == 0) {
      tix[wq][r] = -1;
    }
    __syncthreads();
  }
  const int tot = 4 * top_k * 128;
  for (int l = tid; l < tot; l += 256) {
    int q = l / (top_k * 128);
    int rem = l - q * top_k * 128;
    int r = rem >> 7;
    int e4 = rem & 127;
    int t = tix[q][r];
    float4 v = make_float4(0.f, 0.f, 0.f, 0.f);
    if (t >= 0) v = ((const float4*)(values + (size_t)sel[t] * EDIM))[e4];
    ((float4*)out)[(((size_t)(qb + q) * top_k) + r) * 128 + e4] = v;
  }
}

extern "C" void kernel_launch(void* const* d_in, const int* in_sizes, int n_in,
                              void* d_out, int out_size, void* d_ws, size_t ws_size,
                              hipStream_t stream) {
  const float* keys   = (const float*)d_in[0];
  const float* values = (const float*)d_in[1];
  const float* scores = (const float*)d_in[2];
  const float* qe     = (const float*)d_in[3];
  const float* W_ih   = (const float*)d_in[6];
  const float* W_hh   = (const float*)d_in[7];
  const float* b_ih   = (const float*)d_in[8];
  const float* b_hh   = (const float*)d_in[9];
  const float* W_out  = (const float*)d_in[10];
  const float* b_out  = (const float*)d_in[11];
  float* out = (float*)d_out;
  const int top_k = out_size / (256 * 512);   // = 8

  char* ws = (char*)d_ws;
  int*   nsel   = (int*)ws;                             // 4 B
  int*   sel    = (int*)(ws + 4096);                    // 8 KB
  float* dens   = (float*)(ws + 16384);                 // 9 KB
  float* Hout   = (float*)(ws + (size_t)(1u << 20));    // 4 MB  [1M,5M)
  float* Gin    = (float*)(ws + (size_t)(9u << 20));    // 16 MB [9M,25M)
  float* memo   = (float*)(ws + (size_t)(9u << 20));    // 4 MB, aliases Gin (dead by then)
  (void)in_sizes; (void)n_in; (void)ws_size;

  k_init<<<1024, 256, 0, stream>>>((float4*)Hout);
  k_compact<<<1, 1024, 0, stream>>>(scores, sel, nsel);
  k_gemm<true ><<<dim3(64, 32), 256, 0, stream>>>(keys, W_ih, b_ih, b_hh, Gin, sel, nsel, GJ);
  k_lstm<<<NW, 512, 0, stream>>>(Gin, Hout, W_hh, nsel);
  k_gemm<false><<<dim3(64, 8), 256, 0, stream>>>(Hout, W_out, b_out, nullptr, memo, nullptr, nsel, EDIM);
  k_norms<<<576, 256, 0, stream>>>(memo, qe, dens, nsel);
  k_retrieve<<<64, 256, 0, stream>>>(memo, qe, dens, values, sel, nsel, out, top_k);
}